// Round 11
// baseline (124.280 us; speedup 1.0000x reference)
//
#include <hip/hip_runtime.h>

#define BB 4
#define LL 1024
#define DD 1024
#define HH 16
#define HDD 64

typedef __bf16 bf16x8 __attribute__((ext_vector_type(8)));
typedef float f32x4 __attribute__((ext_vector_type(4)));
typedef float f32x16 __attribute__((ext_vector_type(16)));
typedef unsigned short u16x8 __attribute__((ext_vector_type(8)));
typedef unsigned short u16x4 __attribute__((ext_vector_type(4)));
typedef unsigned int u32x4v __attribute__((ext_vector_type(4)));
typedef unsigned int u32x2 __attribute__((ext_vector_type(2)));

#define LOG2E 1.4426950408889634f

__device__ __forceinline__ unsigned short f2bf(float f) {
    unsigned int u = __builtin_bit_cast(unsigned int, f);
    u += 0x7FFFu + ((u >> 16) & 1u);
    return (unsigned short)(u >> 16);
}

__device__ __forceinline__ unsigned int cvtpk_bf16(float lo, float hi) {
    unsigned int r;
    asm("v_cvt_pk_bf16_f32 %0, %1, %2" : "=v"(r) : "v"(lo), "v"(hi));
    return r;
}

// ---------------- prep: x fp32 -> bf16 ----------------
__global__ __launch_bounds__(256) void cvt_x(const float* __restrict__ x,
                                             unsigned short* __restrict__ xb) {
    const int i = (blockIdx.x * 256 + threadIdx.x) * 8;
    f32x4 a0 = *(const f32x4*)(x + i);
    f32x4 a1 = *(const f32x4*)(x + i + 4);
    u16x8 o;
#pragma unroll
    for (int j = 0; j < 4; ++j) { o[j] = f2bf(a0[j]); o[4 + j] = f2bf(a1[j]); }
    *(u16x8*)(xb + i) = o;
}

// ---------------- prep: W (K-major) -> W^T bf16 (N-major) ----------------
__global__ __launch_bounds__(256) void trans_w(const float* __restrict__ Wq,
                                               const float* __restrict__ Wk,
                                               const float* __restrict__ Wv,
                                               const float* __restrict__ Wo,
                                               unsigned short* __restrict__ Wqkv_t,
                                               unsigned short* __restrict__ Wo_t) {
    __shared__ unsigned short lds[64 * 72];
    const int t = threadIdx.x;
    const int mat = blockIdx.z;
    const float* W = (mat == 0) ? Wq : (mat == 1) ? Wk : (mat == 2) ? Wv : Wo;
    unsigned short* out = (mat < 3) ? (Wqkv_t + (size_t)mat * 1024 * 1024) : Wo_t;
    const int k0 = blockIdx.x * 64;
    const int n0 = blockIdx.y * 64;
#pragma unroll
    for (int p = 0; p < 4; ++p) {
        int c = t + p * 256;
        int kr = c >> 4, c4 = (c & 15) * 4;
        f32x4 v = *(const f32x4*)(W + (size_t)(k0 + kr) * 1024 + n0 + c4);
#pragma unroll
        for (int i = 0; i < 4; ++i) lds[(c4 + i) * 72 + kr] = f2bf(v[i]);
    }
    __syncthreads();
#pragma unroll
    for (int p = 0; p < 2; ++p) {
        int c = t + p * 256;
        int nr = c >> 3, koff = (c & 7) * 8;
        u16x8 vv = *(const u16x8*)&lds[nr * 72 + koff];
        *(u16x8*)(out + (size_t)(n0 + nr) * 1024 + k0 + koff) = vv;
    }
}

// ---------------- bias table, lane-ordered f32 ----------------
// btab3[((bh*8+ci)*2+g)*512 + tg*16 + r] = bias(b,h,ci, j = tg*32+(r&3)+8*(r>>2)+4g)*LOG2E
__global__ __launch_bounds__(256) void bias_prep3(const int* __restrict__ cid,
                                                  const int* __restrict__ vmask,
                                                  const float* __restrict__ case_bias,
                                                  const float* __restrict__ verb_bias,
                                                  float* __restrict__ btab3) {
    const int bh = blockIdx.x;
    const int b = bh >> 4, h = bh & 15;
    const float vbh = verb_bias[h] * LOG2E;
    for (int idx = threadIdx.x; idx < 8192; idx += 256) {
        const int ci = idx >> 10;
        const int g = (idx >> 9) & 1;
        const int pos = idx & 511;
        const int tg = pos >> 4, r = pos & 15;
        const int j = tg * 32 + (r & 3) + 8 * (r >> 2) + 4 * g;
        const int cj = cid[b * LL + j];
        const float vb = vmask[b * LL + j] ? vbh : 0.f;
        btab3[(size_t)bh * 8192 + idx] = case_bias[h * 64 + ci * 8 + cj] * LOG2E + vb;
    }
}

// ---------------- QKV GEMM ----------------
__global__ __launch_bounds__(256) void gemm_qkv(const unsigned short* __restrict__ Abf,
                                                const unsigned short* __restrict__ Btw,
                                                const float* __restrict__ bq,
                                                const float* __restrict__ bk,
                                                const float* __restrict__ bv,
                                                unsigned short* __restrict__ qkv) {
    __shared__ unsigned short Asm[128 * 32];
    __shared__ unsigned short Bsm[128 * 32];
    const int t = threadIdx.x;
    const int w = t >> 6, lane = t & 63;
    const int wm = w >> 1, wn = w & 1;
    const int lr = lane & 15, lk = (lane >> 4) * 8;
    const int row0 = blockIdx.x * 128;
    const int col0 = blockIdx.y * 128;
    const int r = t >> 2;
    const int cb8 = (t & 3) * 8;

    f32x4 acc[4][4];
#pragma unroll
    for (int mf = 0; mf < 4; ++mf)
#pragma unroll
        for (int nf = 0; nf < 4; ++nf)
#pragma unroll
            for (int e = 0; e < 4; ++e) acc[mf][nf][e] = 0.f;

    for (int kt = 0; kt < 32; ++kt) {
        __syncthreads();
        const int k0 = kt * 32;
#pragma unroll
        for (int p = 0; p < 2; ++p) {
            const unsigned short* sa = Abf + (size_t)(row0 + p * 64 + r) * 1024 + k0 + cb8;
            __builtin_amdgcn_global_load_lds(
                (const __attribute__((address_space(1))) unsigned int*)sa,
                (__attribute__((address_space(3))) unsigned int*)(Asm + p * 2048 + t * 8), 16, 0, 0);
            const unsigned short* sb = Btw + (size_t)(col0 + p * 64 + r) * 1024 + k0 + cb8;
            __builtin_amdgcn_global_load_lds(
                (const __attribute__((address_space(1))) unsigned int*)sb,
                (__attribute__((address_space(3))) unsigned int*)(Bsm + p * 2048 + t * 8), 16, 0, 0);
        }
        __syncthreads();
        bf16x8 af[4], bfr[4];
#pragma unroll
        for (int mf = 0; mf < 4; ++mf)
            af[mf] = *(const bf16x8*)&Asm[(wm * 64 + mf * 16 + lr) * 32 + lk];
#pragma unroll
        for (int nf = 0; nf < 4; ++nf)
            bfr[nf] = *(const bf16x8*)&Bsm[(wn * 64 + nf * 16 + lr) * 32 + lk];
#pragma unroll
        for (int mf = 0; mf < 4; ++mf)
#pragma unroll
            for (int nf = 0; nf < 4; ++nf)
                acc[mf][nf] = __builtin_amdgcn_mfma_f32_16x16x32_bf16(af[mf], bfr[nf], acc[mf][nf], 0, 0, 0);
    }

#pragma unroll
    for (int mf = 0; mf < 4; ++mf) {
        const int grow = row0 + wm * 64 + mf * 16 + (lane >> 4) * 4;
#pragma unroll
        for (int nf = 0; nf < 4; ++nf) {
            const int gcol = col0 + wn * 64 + nf * 16 + lr;
            const int mat = gcol >> 10;
            const int nc_ = gcol & 1023;
            const float bias = (mat == 0) ? bq[nc_] : (mat == 1 ? bk[nc_] : bv[nc_]);
            const float scale = (mat == 0) ? 0.125f * LOG2E : 1.0f;
            const int hh = nc_ >> 6, hd = nc_ & 63;
#pragma unroll
            for (int rr = 0; rr < 4; ++rr) {
                const int row = grow + rr;
                const int bb = row >> 10, ll = row & 1023;
                const float vout = (acc[mf][nf][rr] + bias) * scale;
                qkv[((((size_t)mat * BB + bb) * HH + hh) * LL + ll) * HDD + hd] = f2bf(vout);
            }
        }
    }
}

// ---------------- V transpose per head: [L][64] -> [64][L] ----------------
__global__ __launch_bounds__(256) void vtrans(const unsigned short* __restrict__ Vg,
                                              unsigned short* __restrict__ Vt) {
    __shared__ unsigned short lds[64 * 72];
    const int t = threadIdx.x;
    const int bh = blockIdx.y;
    const int j0 = blockIdx.x * 64;
    const size_t hoff = (size_t)bh * LL * HDD;
#pragma unroll
    for (int p = 0; p < 2; ++p) {
        int c = t + p * 256;
        int jr = c >> 3, doff = (c & 7) * 8;
        u16x8 v = *(const u16x8*)(Vg + hoff + (size_t)(j0 + jr) * 64 + doff);
#pragma unroll
        for (int i = 0; i < 8; ++i) lds[(doff + i) * 72 + jr] = v[i];
    }
    __syncthreads();
#pragma unroll
    for (int p = 0; p < 2; ++p) {
        int c = t + p * 256;
        int dr = c >> 3, joff = (c & 7) * 8;
        u16x8 vv = *(const u16x8*)&lds[dr * 72 + joff];
        *(u16x8*)(Vt + hoff + (size_t)dr * 1024 + j0 + joff) = vv;
    }
}

// ---------------- attention v10: wave-private staging, ZERO barriers ----------------
// Each wave owns 32 q-rows x all j; KVBLK=32; private double-buffered 16KB LDS;
// per-wave vmcnt(0) pipeline (vmcnt is per-wave) -> no block-wide rendezvous at all.
__device__ __forceinline__ void ctile32(const unsigned short* kb, const f32x4 (&bb)[4],
                                        const bf16x8 (&qf)[4], int q31, int g,
                                        f32x16& acc0, f32x16& acc1, f32x16& sum16) {
    // ---- QK^T (S^T[32j][32q]): bias f32 lane-ordered in C-init ----
    f32x16 s;
#pragma unroll
    for (int r = 0; r < 16; ++r) s[r] = bb[r >> 2][r & 3];
    const int swz = q31 & 7;
    __builtin_amdgcn_s_setprio(1);
#pragma unroll
    for (int kk = 0; kk < 4; ++kk) {
        const bf16x8 af = *(const bf16x8*)&kb[q31 * 64 + (((2 * kk + g) ^ swz) * 8)];
        s = __builtin_amdgcn_mfma_f32_32x32x16_bf16(af, qf[kk], s, 0, 0, 0);
    }
    __builtin_amdgcn_s_setprio(0);

    // ---- static-max softmax: p = exp2(s), SIMD sum accumulation ----
#pragma unroll
    for (int r = 0; r < 16; ++r) {
        const float p = __builtin_amdgcn_exp2f(s[r]);
        s[r] = p;
        sum16[r] += p;
    }

    // ---- P -> bf16 B-frags (cvt_pk + permlane32_swap), PV ----
    __builtin_amdgcn_s_setprio(1);
#pragma unroll
    for (int ks = 0; ks < 2; ++ks) {
        const int rb = ks * 8;
        unsigned int a0 = cvtpk_bf16(s[rb + 0], s[rb + 1]);
        unsigned int b0 = cvtpk_bf16(s[rb + 4], s[rb + 5]);
        unsigned int a1 = cvtpk_bf16(s[rb + 2], s[rb + 3]);
        unsigned int b1 = cvtpk_bf16(s[rb + 6], s[rb + 7]);
        u32x2 r0 = __builtin_amdgcn_permlane32_swap(a0, b0, false, false);
        u32x2 r1 = __builtin_amdgcn_permlane32_swap(a1, b1, false, false);
        u32x4v pw;
        pw[0] = r0[0]; pw[1] = r1[0]; pw[2] = r0[1]; pw[3] = r1[1];
        const bf16x8 pf = __builtin_bit_cast(bf16x8, pw);
#pragma unroll
        for (int dt = 0; dt < 2; ++dt) {
            const int vrow = dt * 32 + q31;
            const bf16x8 vf =
                *(const bf16x8*)&kb[2048 + vrow * 32 + (((2 * ks + g) ^ ((vrow >> 1) & 3)) * 8)];
            if (dt == 0)
                acc0 = __builtin_amdgcn_mfma_f32_32x32x16_bf16(vf, pf, acc0, 0, 0, 0);
            else
                acc1 = __builtin_amdgcn_mfma_f32_32x32x16_bf16(vf, pf, acc1, 0, 0, 0);
        }
    }
    __builtin_amdgcn_s_setprio(0);
}

__global__ __launch_bounds__(256, 2) void attn10(const unsigned short* __restrict__ Qg,
                                                 const unsigned short* __restrict__ Kg,
                                                 const unsigned short* __restrict__ Vtg,
                                                 const int* __restrict__ cid,
                                                 const float* __restrict__ btab3,
                                                 unsigned short* __restrict__ att) {
    __shared__ unsigned short kvbuf[4][8192];  // 64 KiB: 16 KB per wave (2 bufs x (K 2048 + V 2048 sh))

    const int t = threadIdx.x;
    const int w = t >> 6;
    const int lane = t & 63;
    const int q31 = lane & 31;
    const int g = lane >> 5;
    const int r8 = lane >> 3, c8 = lane & 7;
    const int r4 = lane >> 2, c4 = lane & 3;

    // XCD-aware decode: all 8 q-tiles of a head on the same XCD (K/V L2-resident)
    const int f = blockIdx.x;
    const int qt = (f >> 3) & 7;
    const int bh = ((f & 7) << 3) | (f >> 6);
    const int b = bh >> 4, h = bh & 15;
    const size_t headoff = (size_t)bh * LL * HDD;
    const int q0 = qt * 128;
    const int qrow = q0 + w * 32 + q31;

    bf16x8 qf[4];
    {
        const unsigned short* qp = Qg + headoff + (size_t)qrow * HDD + g * 8;
        qf[0] = *(const bf16x8*)(qp);
        qf[1] = *(const bf16x8*)(qp + 16);
        qf[2] = *(const bf16x8*)(qp + 32);
        qf[3] = *(const bf16x8*)(qp + 48);
    }
    const int ci = cid[b * LL + qrow];
    const float* bbase = btab3 + ((size_t)(bh * 8 + ci) * 2 + g) * 512;

    unsigned short* kpriv = &kvbuf[w][0];

#define STAGE(boff, j0s)                                                                           \
    {                                                                                              \
        _Pragma("unroll") for (int cc = 0; cc < 4; ++cc) {                                         \
            const int rowk = cc * 8 + r8;                                                          \
            const unsigned short* srck =                                                           \
                Kg + headoff + (size_t)((j0s) + rowk) * HDD + ((c8 ^ (rowk & 7)) * 8);             \
            __builtin_amdgcn_global_load_lds(                                                      \
                (const __attribute__((address_space(1))) unsigned int*)srck,                       \
                (__attribute__((address_space(3))) unsigned int*)(kpriv + (boff) + cc * 512), 16,  \
                0, 0);                                                                             \
            const int dv = cc * 16 + r4;                                                           \
            const unsigned short* srcv =                                                           \
                Vtg + headoff + (size_t)dv * LL + (j0s) + ((c4 ^ ((dv >> 1) & 3)) * 8);            \
            __builtin_amdgcn_global_load_lds(                                                      \
                (const __attribute__((address_space(1))) unsigned int*)srcv,                       \
                (__attribute__((address_space(3))) unsigned int*)(kpriv + (boff) + 2048 +          \
                                                                  cc * 512),                      \
                16, 0, 0);                                                                         \
        }                                                                                          \
    }

    f32x16 acc0, acc1, sum16;
#pragma unroll
    for (int e = 0; e < 16; ++e) { acc0[e] = 0.f; acc1[e] = 0.f; sum16[e] = 0.f; }

    f32x4 bA[4], bB[4];
    STAGE(0, 0);
#pragma unroll
    for (int i = 0; i < 4; ++i) bA[i] = *(const f32x4*)(bbase + 4 * i);

    for (int jt = 0; jt < 32; jt += 2) {
        asm volatile("s_waitcnt vmcnt(0)" ::: "memory");  // own buf0 loads landed
        if (jt + 1 < 32) {
            STAGE(4096, (jt + 1) * 32);
#pragma unroll
            for (int i = 0; i < 4; ++i) bB[i] = *(const f32x4*)(bbase + (jt + 1) * 16 + 4 * i);
        }
        ctile32(kpriv, bA, qf, q31, g, acc0, acc1, sum16);

        asm volatile("s_waitcnt vmcnt(0)" ::: "memory");  // own buf1 loads landed
        if (jt + 2 < 32) {
            STAGE(0, (jt + 2) * 32);
#pragma unroll
            for (int i = 0; i < 4; ++i) bA[i] = *(const f32x4*)(bbase + (jt + 2) * 16 + 4 * i);
        }
        ctile32(kpriv + 4096, bB, qf, q31, g, acc0, acc1, sum16);
    }
#undef STAGE

    // ---- final row-sum reduce (once) ----
    float l_run = 0.f;
#pragma unroll
    for (int e = 0; e < 16; ++e) l_run += sum16[e];
    l_run += __shfl_xor(l_run, 32);
    const float inv = 1.0f / l_run;

    // ---- epilogue: wave-private out^T -> own LDS (swizzled) -> coalesced store ----
    unsigned short* ob = kpriv;  // reuse own region (all own reads complete, same-wave ordering)
    const int oswz = (q31 & 7) << 3;
#pragma unroll
    for (int dt = 0; dt < 2; ++dt) {
#pragma unroll
        for (int u = 0; u < 4; ++u) {
            u16x4 v4;
#pragma unroll
            for (int v = 0; v < 4; ++v)
                v4[v] = f2bf((dt ? acc1[4 * u + v] : acc0[4 * u + v]) * inv);
            const int d0 = dt * 32 + 8 * u + 4 * g;
            *(u16x4*)&ob[q31 * 64 + (d0 ^ oswz)] = v4;
        }
    }
#pragma unroll
    for (int p = 0; p < 4; ++p) {
        const int row = p * 8 + r8;
        u16x8 v = *(const u16x8*)&ob[row * 64 + ((c8 ^ (row & 7)) * 8)];
        *(u16x8*)(att + (size_t)(b * LL + q0 + w * 32 + row) * DD + h * 64 + c8 * 8) = v;
    }
}

// ---------------- out GEMM: att[4096x1024] x Wo -> fp32 out ----------------
__global__ __launch_bounds__(256) void gemm_out(const unsigned short* __restrict__ Abf,
                                                const unsigned short* __restrict__ Btw,
                                                const float* __restrict__ bo,
                                                float* __restrict__ out) {
    __shared__ unsigned short Asm[128 * 32];
    __shared__ unsigned short Bsm[128 * 32];
    const int t = threadIdx.x;
    const int w = t >> 6, lane = t & 63;
    const int wm = w >> 1, wn = w & 1;
    const int lr = lane & 15, lk = (lane >> 4) * 8;
    const int row0 = blockIdx.x * 128;
    const int col0 = blockIdx.y * 128;
    const int r = t >> 2;
    const int cb8 = (t & 3) * 8;

    f32x4 acc[4][4];
#pragma unroll
    for (int mf = 0; mf < 4; ++mf)
#pragma unroll
        for (int nf = 0; nf < 4; ++nf)
#pragma unroll
            for (int e = 0; e < 4; ++e) acc[mf][nf][e] = 0.f;

    for (int kt = 0; kt < 32; ++kt) {
        __syncthreads();
        const int k0 = kt * 32;
#pragma unroll
        for (int p = 0; p < 2; ++p) {
            const unsigned short* sa = Abf + (size_t)(row0 + p * 64 + r) * 1024 + k0 + cb8;
            __builtin_amdgcn_global_load_lds(
                (const __attribute__((address_space(1))) unsigned int*)sa,
                (__attribute__((address_space(3))) unsigned int*)(Asm + p * 2048 + t * 8), 16, 0, 0);
            const unsigned short* sb = Btw + (size_t)(col0 + p * 64 + r) * 1024 + k0 + cb8;
            __builtin_amdgcn_global_load_lds(
                (const __attribute__((address_space(1))) unsigned int*)sb,
                (__attribute__((address_space(3))) unsigned int*)(Bsm + p * 2048 + t * 8), 16, 0, 0);
        }
        __syncthreads();
        bf16x8 af[4], bfr[4];
#pragma unroll
        for (int mf = 0; mf < 4; ++mf)
            af[mf] = *(const bf16x8*)&Asm[(wm * 64 + mf * 16 + lr) * 32 + lk];
#pragma unroll
        for (int nf = 0; nf < 4; ++nf)
            bfr[nf] = *(const bf16x8*)&Bsm[(wn * 64 + nf * 16 + lr) * 32 + lk];
#pragma unroll
        for (int mf = 0; mf < 4; ++mf)
#pragma unroll
            for (int nf = 0; nf < 4; ++nf)
                acc[mf][nf] = __builtin_amdgcn_mfma_f32_16x16x32_bf16(af[mf], bfr[nf], acc[mf][nf], 0, 0, 0);
    }

#pragma unroll
    for (int mf = 0; mf < 4; ++mf) {
        const int grow = row0 + wm * 64 + mf * 16 + (lane >> 4) * 4;
#pragma unroll
        for (int nf = 0; nf < 4; ++nf) {
            const int gcol = col0 + wn * 64 + nf * 16 + lr;
            const float bias = bo[gcol];
#pragma unroll
            for (int rr = 0; rr < 4; ++rr)
                out[(size_t)(grow + rr) * 1024 + gcol] = acc[mf][nf][rr] + bias;
        }
    }
}

extern "C" void kernel_launch(void* const* d_in, const int* in_sizes, int n_in,
                              void* d_out, int out_size, void* d_ws, size_t ws_size,
                              hipStream_t stream) {
    const float* x = (const float*)d_in[0];
    const int* cid = (const int*)d_in[1];
    const int* vmask = (const int*)d_in[2];
    const float* Wq = (const float*)d_in[3];
    const float* bq = (const float*)d_in[4];
    const float* Wk = (const float*)d_in[5];
    const float* bk = (const float*)d_in[6];
    const float* Wv = (const float*)d_in[7];
    const float* bv = (const float*)d_in[8];
    const float* Wo = (const float*)d_in[9];
    const float* bo = (const float*)d_in[10];
    const float* case_bias = (const float*)d_in[11];
    const float* verb_bias = (const float*)d_in[12];
    float* out = (float*)d_out;

    char* ws = (char*)d_ws;
    unsigned short* xb     = (unsigned short*)(ws);                       // 8 MB
    unsigned short* Wqkv_t = (unsigned short*)(ws + ((size_t)8 << 20));   // 6 MB
    unsigned short* Wo_t   = (unsigned short*)(ws + ((size_t)14 << 20));  // 2 MB
    unsigned short* qkv    = (unsigned short*)(ws + ((size_t)16 << 20));  // 24 MB
    unsigned short* Vt     = (unsigned short*)(ws + ((size_t)40 << 20));  // 8 MB
    unsigned short* att    = (unsigned short*)(ws + ((size_t)48 << 20));  // 8 MB
    float*          btab3  = (float*)(ws + ((size_t)56 << 20));           // 2 MB

    const size_t MATSZ = (size_t)BB * HH * LL * HDD;  // 4 Mi elements

    hipLaunchKernelGGL(cvt_x, dim3(2048), dim3(256), 0, stream, x, xb);
    hipLaunchKernelGGL(trans_w, dim3(16, 16, 4), dim3(256), 0, stream, Wq, Wk, Wv, Wo, Wqkv_t, Wo_t);
    hipLaunchKernelGGL(bias_prep3, dim3(64), dim3(256), 0, stream, cid, vmask, case_bias, verb_bias, btab3);
    hipLaunchKernelGGL(gemm_qkv, dim3(32, 24), dim3(256), 0, stream, xb, Wqkv_t, bq, bk, bv, qkv);
    hipLaunchKernelGGL(vtrans, dim3(16, 64), dim3(256), 0, stream, qkv + 2 * MATSZ, Vt);
    hipLaunchKernelGGL(attn10, dim3(512), dim3(256), 0, stream,
                       qkv, qkv + MATSZ, Vt, cid, btab3, att);
    hipLaunchKernelGGL(gemm_out, dim3(32, 8), dim3(256), 0, stream, att, Wo_t, bo, out);
}

// Round 12
// 98.501 us; speedup vs baseline: 1.2617x; 1.2617x over previous
//
#include <hip/hip_runtime.h>

#define BB 4
#define LL 1024
#define DD 1024
#define HH 16
#define HDD 64

typedef __bf16 bf16x8 __attribute__((ext_vector_type(8)));
typedef float f32x4 __attribute__((ext_vector_type(4)));
typedef float f32x16 __attribute__((ext_vector_type(16)));
typedef unsigned short u16x8 __attribute__((ext_vector_type(8)));
typedef unsigned short u16x4 __attribute__((ext_vector_type(4)));
typedef unsigned int u32x4v __attribute__((ext_vector_type(4)));
typedef unsigned int u32x2 __attribute__((ext_vector_type(2)));

#define LOG2E 1.4426950408889634f

__device__ __forceinline__ unsigned short f2bf(float f) {
    unsigned int u = __builtin_bit_cast(unsigned int, f);
    u += 0x7FFFu + ((u >> 16) & 1u);
    return (unsigned short)(u >> 16);
}

__device__ __forceinline__ unsigned int cvtpk_bf16(float lo, float hi) {
    unsigned int r;
    asm("v_cvt_pk_bf16_f32 %0, %1, %2" : "=v"(r) : "v"(lo), "v"(hi));
    return r;
}

// ---------------- merged prep: trans_w (z=0..3) | cvt_x (z=4) | bias_prep (z=5) ----------------
__global__ __launch_bounds__(256) void prep_all(const float* __restrict__ x,
                                                const float* __restrict__ Wq,
                                                const float* __restrict__ Wk,
                                                const float* __restrict__ Wv,
                                                const float* __restrict__ Wo,
                                                const int* __restrict__ cid,
                                                const int* __restrict__ vmask,
                                                const float* __restrict__ case_bias,
                                                const float* __restrict__ verb_bias,
                                                unsigned short* __restrict__ xb,
                                                unsigned short* __restrict__ Wqkv_t,
                                                unsigned short* __restrict__ Wo_t,
                                                float* __restrict__ btab) {
    __shared__ unsigned short lds[64 * 72];
    const int t = threadIdx.x;
    const int z = blockIdx.z;

    if (z < 4) {
        // ---- trans_w: W (K-major) -> W^T bf16 (N-major) ----
        const int mat = z;
        const float* W = (mat == 0) ? Wq : (mat == 1) ? Wk : (mat == 2) ? Wv : Wo;
        unsigned short* out = (mat < 3) ? (Wqkv_t + (size_t)mat * 1024 * 1024) : Wo_t;
        const int k0 = blockIdx.x * 64;
        const int n0 = blockIdx.y * 64;
#pragma unroll
        for (int p = 0; p < 4; ++p) {
            int c = t + p * 256;
            int kr = c >> 4, c4 = (c & 15) * 4;
            f32x4 v = *(const f32x4*)(W + (size_t)(k0 + kr) * 1024 + n0 + c4);
#pragma unroll
            for (int i = 0; i < 4; ++i) lds[(c4 + i) * 72 + kr] = f2bf(v[i]);
        }
        __syncthreads();
#pragma unroll
        for (int p = 0; p < 2; ++p) {
            int c = t + p * 256;
            int nr = c >> 3, koff = (c & 7) * 8;
            u16x8 vv = *(const u16x8*)&lds[nr * 72 + koff];
            *(u16x8*)(out + (size_t)(n0 + nr) * 1024 + k0 + koff) = vv;
        }
    } else if (z == 4) {
        // ---- cvt_x: 4Mi f32 -> bf16, 65536 threads x 8 passes x 8 elems ----
        const int bid = blockIdx.y * 16 + blockIdx.x;
        const int base = (bid * 256 + t) * 8;
#pragma unroll
        for (int p = 0; p < 8; ++p) {
            const int i = base + p * 524288;
            f32x4 a0 = *(const f32x4*)(x + i);
            f32x4 a1 = *(const f32x4*)(x + i + 4);
            u16x8 o;
#pragma unroll
            for (int j = 0; j < 4; ++j) { o[j] = f2bf(a0[j]); o[4 + j] = f2bf(a1[j]); }
            *(u16x8*)(xb + i) = o;
        }
    } else {
        // ---- bias_prep: btab[bh][ci][j] = (case+verb)*LOG2E (f32), bh = bid<64 ----
        const int bid = blockIdx.y * 16 + blockIdx.x;
        if (bid < 64) {
            const int bh = bid;
            const int b = bh >> 4, h = bh & 15;
            const float vbh = verb_bias[h] * LOG2E;
#pragma unroll
            for (int p = 0; p < 4; ++p) {
                const int j = t + p * 256;
                const int cj = cid[b * LL + j];
                const float vb = vmask[b * LL + j] ? vbh : 0.f;
#pragma unroll
                for (int ci = 0; ci < 8; ++ci)
                    btab[((size_t)bh * 8 + ci) * LL + j] =
                        case_bias[h * 64 + ci * 8 + cj] * LOG2E + vb;
            }
        }
    }
}

// ---------------- QKV GEMM ----------------
__global__ __launch_bounds__(256) void gemm_qkv(const unsigned short* __restrict__ Abf,
                                                const unsigned short* __restrict__ Btw,
                                                const float* __restrict__ bq,
                                                const float* __restrict__ bk,
                                                const float* __restrict__ bv,
                                                unsigned short* __restrict__ qkv) {
    __shared__ unsigned short Asm[128 * 32];
    __shared__ unsigned short Bsm[128 * 32];
    const int t = threadIdx.x;
    const int w = t >> 6, lane = t & 63;
    const int wm = w >> 1, wn = w & 1;
    const int lr = lane & 15, lk = (lane >> 4) * 8;
    const int row0 = blockIdx.x * 128;
    const int col0 = blockIdx.y * 128;
    const int r = t >> 2;
    const int cb8 = (t & 3) * 8;

    f32x4 acc[4][4];
#pragma unroll
    for (int mf = 0; mf < 4; ++mf)
#pragma unroll
        for (int nf = 0; nf < 4; ++nf)
#pragma unroll
            for (int e = 0; e < 4; ++e) acc[mf][nf][e] = 0.f;

    for (int kt = 0; kt < 32; ++kt) {
        __syncthreads();
        const int k0 = kt * 32;
#pragma unroll
        for (int p = 0; p < 2; ++p) {
            const unsigned short* sa = Abf + (size_t)(row0 + p * 64 + r) * 1024 + k0 + cb8;
            __builtin_amdgcn_global_load_lds(
                (const __attribute__((address_space(1))) unsigned int*)sa,
                (__attribute__((address_space(3))) unsigned int*)(Asm + p * 2048 + t * 8), 16, 0, 0);
            const unsigned short* sb = Btw + (size_t)(col0 + p * 64 + r) * 1024 + k0 + cb8;
            __builtin_amdgcn_global_load_lds(
                (const __attribute__((address_space(1))) unsigned int*)sb,
                (__attribute__((address_space(3))) unsigned int*)(Bsm + p * 2048 + t * 8), 16, 0, 0);
        }
        __syncthreads();
        bf16x8 af[4], bfr[4];
#pragma unroll
        for (int mf = 0; mf < 4; ++mf)
            af[mf] = *(const bf16x8*)&Asm[(wm * 64 + mf * 16 + lr) * 32 + lk];
#pragma unroll
        for (int nf = 0; nf < 4; ++nf)
            bfr[nf] = *(const bf16x8*)&Bsm[(wn * 64 + nf * 16 + lr) * 32 + lk];
#pragma unroll
        for (int mf = 0; mf < 4; ++mf)
#pragma unroll
            for (int nf = 0; nf < 4; ++nf)
                acc[mf][nf] = __builtin_amdgcn_mfma_f32_16x16x32_bf16(af[mf], bfr[nf], acc[mf][nf], 0, 0, 0);
    }

#pragma unroll
    for (int mf = 0; mf < 4; ++mf) {
        const int grow = row0 + wm * 64 + mf * 16 + (lane >> 4) * 4;
#pragma unroll
        for (int nf = 0; nf < 4; ++nf) {
            const int gcol = col0 + wn * 64 + nf * 16 + lr;
            const int mat = gcol >> 10;
            const int nc_ = gcol & 1023;
            const float bias = (mat == 0) ? bq[nc_] : (mat == 1 ? bk[nc_] : bv[nc_]);
            const float scale = (mat == 0) ? 0.125f * LOG2E : 1.0f;
            const int hh = nc_ >> 6, hd = nc_ & 63;
#pragma unroll
            for (int rr = 0; rr < 4; ++rr) {
                const int row = grow + rr;
                const int bb = row >> 10, ll = row & 1023;
                const float vout = (acc[mf][nf][rr] + bias) * scale;
                qkv[((((size_t)mat * BB + bb) * HH + hh) * LL + ll) * HDD + hd] = f2bf(vout);
            }
        }
    }
}

// ---------------- V transpose per head: [L][64] -> [64][L] ----------------
__global__ __launch_bounds__(256) void vtrans(const unsigned short* __restrict__ Vg,
                                              unsigned short* __restrict__ Vt) {
    __shared__ unsigned short lds[64 * 72];
    const int t = threadIdx.x;
    const int bh = blockIdx.y;
    const int j0 = blockIdx.x * 64;
    const size_t hoff = (size_t)bh * LL * HDD;
#pragma unroll
    for (int p = 0; p < 2; ++p) {
        int c = t + p * 256;
        int jr = c >> 3, doff = (c & 7) * 8;
        u16x8 v = *(const u16x8*)(Vg + hoff + (size_t)(j0 + jr) * 64 + doff);
#pragma unroll
        for (int i = 0; i < 8; ++i) lds[(doff + i) * 72 + jr] = v[i];
    }
    __syncthreads();
#pragma unroll
    for (int p = 0; p < 2; ++p) {
        int c = t + p * 256;
        int dr = c >> 3, joff = (c & 7) * 8;
        u16x8 vv = *(const u16x8*)&lds[dr * 72 + joff];
        *(u16x8*)(Vt + hoff + (size_t)dr * 1024 + j0 + joff) = vv;
    }
}

// ---------------- attention v8 (round-9 verified): static-max softmax, 3-buf pipeline ----------------
__global__ __launch_bounds__(256, 2) void attn8(const unsigned short* __restrict__ Qg,
                                                const unsigned short* __restrict__ Kg,
                                                const unsigned short* __restrict__ Vtg,
                                                const int* __restrict__ cid,
                                                const float* __restrict__ btab,
                                                unsigned short* __restrict__ att) {
    __shared__ unsigned short kvbuf[3 * 8192];   // 48 KiB: 3 rotating K/V buffers
    __shared__ unsigned short tblb[8 * 1056];    // 16.5 KiB bias table (bf16), stride 1060 sh

    const int t = threadIdx.x;
    const int w = t >> 6;
    const int lane = t & 63;
    const int q31 = lane & 31;
    const int g = lane >> 5;

    // XCD-aware decode: all 8 q-tiles of a head on the same XCD (K/V L2-resident)
    const int f = blockIdx.x;
    const int qt = (f >> 3) & 7;
    const int bh = ((f & 7) << 3) | (f >> 6);
    const int b = bh >> 4, h = bh & 15;
    const size_t headoff = (size_t)bh * LL * HDD;
    const int q0 = qt * 128;
    const int qrow = q0 + w * 32 + q31;

    bf16x8 qf[4];
    {
        const unsigned short* qp = Qg + headoff + (size_t)qrow * HDD + g * 8;
        qf[0] = *(const bf16x8*)(qp);
        qf[1] = *(const bf16x8*)(qp + 16);
        qf[2] = *(const bf16x8*)(qp + 32);
        qf[3] = *(const bf16x8*)(qp + 48);
    }
    const int ci = cid[b * LL + qrow];
    const int tb_lane = ci * 1060 + 4 * g;

    const int r8 = lane >> 3, c8 = lane & 7;

#define STAGE(base_sh, j0s)                                                                        \
    {                                                                                              \
        _Pragma("unroll") for (int cc = 0; cc < 2; ++cc) {                                         \
            const int chunk = w + cc * 4;                                                          \
            const int row = chunk * 8 + r8;                                                        \
            const int sc8 = (c8 ^ (row & 7)) * 8;                                                  \
            const unsigned short* srck = Kg + headoff + (size_t)((j0s) + row) * HDD + sc8;         \
            __builtin_amdgcn_global_load_lds(                                                      \
                (const __attribute__((address_space(1))) unsigned int*)srck,                       \
                (__attribute__((address_space(3))) unsigned int*)(&kvbuf[(base_sh) + chunk * 512]),\
                16, 0, 0);                                                                         \
            const unsigned short* srcv = Vtg + headoff + (size_t)row * LL + (j0s) + sc8;           \
            __builtin_amdgcn_global_load_lds(                                                      \
                (const __attribute__((address_space(1))) unsigned int*)srcv,                       \
                (__attribute__((address_space(3))) unsigned int*)(&kvbuf[(base_sh) + 4096 +        \
                                                                         chunk * 512]),           \
                16, 0, 0);                                                                         \
        }                                                                                          \
    }

    // prologue: stage tiles 0,1; build bias table; one full drain
    STAGE(0, 0);
    STAGE(8192, 64);
    for (int e = t; e < 8192; e += 256) {
        const int cie = e >> 10, j = e & 1023;
        tblb[cie * 1060 + j] = f2bf(btab[(size_t)bh * 8192 + e]);
    }
    __syncthreads();

    f32x16 acc0, acc1, sum16;
#pragma unroll
    for (int e = 0; e < 16; ++e) { acc0[e] = 0.f; acc1[e] = 0.f; sum16[e] = 0.f; }

    int cur = 0, stg = 2;
    for (int jt = 0; jt < 16; ++jt) {
        if (jt == 15) asm volatile("s_waitcnt vmcnt(0)" ::: "memory");
        else          asm volatile("s_waitcnt vmcnt(4)" ::: "memory");
        __builtin_amdgcn_s_barrier();
        asm volatile("" ::: "memory");

        if (jt < 14) STAGE(stg * 8192, (jt + 2) * 64);

        const unsigned short* kvb = &kvbuf[cur * 8192];

        // ---- QK^T (S^T): bias C-init from LDS bf16 table ----
        f32x16 st[2];
#pragma unroll
        for (int jt2 = 0; jt2 < 2; ++jt2) {
            f32x16 s;
#pragma unroll
            for (int q = 0; q < 4; ++q) {
                const u32x2 bw = *(const u32x2*)&tblb[tb_lane + jt * 64 + jt2 * 32 + 8 * q];
                s[4 * q + 0] = __builtin_bit_cast(float, bw[0] << 16);
                s[4 * q + 1] = __builtin_bit_cast(float, bw[0] & 0xFFFF0000u);
                s[4 * q + 2] = __builtin_bit_cast(float, bw[1] << 16);
                s[4 * q + 3] = __builtin_bit_cast(float, bw[1] & 0xFFFF0000u);
            }
            const int arow = jt2 * 32 + q31;
            const unsigned short* kb = &kvb[arow * 64];
            const int swz = arow & 7;
            __builtin_amdgcn_s_setprio(1);
#pragma unroll
            for (int kk = 0; kk < 4; ++kk) {
                bf16x8 af = *(const bf16x8*)&kb[((2 * kk + g) ^ swz) * 8];
                s = __builtin_amdgcn_mfma_f32_32x32x16_bf16(af, qf[kk], s, 0, 0, 0);
            }
            __builtin_amdgcn_s_setprio(0);
            st[jt2] = s;
        }

        // ---- static-max softmax: p = exp2(s); SIMD-wise sum accumulation ----
#pragma unroll
        for (int jt2 = 0; jt2 < 2; ++jt2)
#pragma unroll
            for (int r = 0; r < 16; ++r) {
                const float p = __builtin_amdgcn_exp2f(st[jt2][r]);
                st[jt2][r] = p;
                sum16[r] += p;
            }

        // ---- P -> bf16 B-fragments via cvt_pk + permlane32_swap, then PV ----
        __builtin_amdgcn_s_setprio(1);
#pragma unroll
        for (int kk = 0; kk < 4; ++kk) {
            const int jt2 = kk >> 1, rb = (kk & 1) * 8;
            unsigned int a0 = cvtpk_bf16(st[jt2][rb + 0], st[jt2][rb + 1]);
            unsigned int b0 = cvtpk_bf16(st[jt2][rb + 4], st[jt2][rb + 5]);
            unsigned int a1 = cvtpk_bf16(st[jt2][rb + 2], st[jt2][rb + 3]);
            unsigned int b1 = cvtpk_bf16(st[jt2][rb + 6], st[jt2][rb + 7]);
            u32x2 r0 = __builtin_amdgcn_permlane32_swap(a0, b0, false, false);
            u32x2 r1 = __builtin_amdgcn_permlane32_swap(a1, b1, false, false);
            u32x4v pw;
            pw[0] = r0[0]; pw[1] = r1[0]; pw[2] = r0[1]; pw[3] = r1[1];
            const bf16x8 pf = __builtin_bit_cast(bf16x8, pw);
#pragma unroll
            for (int dt = 0; dt < 2; ++dt) {
                const int vrow = dt * 32 + q31;
                const bf16x8 vf =
                    *(const bf16x8*)&kvb[4096 + vrow * 64 + (((2 * kk + g) ^ (vrow & 7)) * 8)];
                if (dt == 0)
                    acc0 = __builtin_amdgcn_mfma_f32_32x32x16_bf16(vf, pf, acc0, 0, 0, 0);
                else
                    acc1 = __builtin_amdgcn_mfma_f32_32x32x16_bf16(vf, pf, acc1, 0, 0, 0);
            }
        }
        __builtin_amdgcn_s_setprio(0);

        cur = (cur == 2) ? 0 : cur + 1;
        stg = (stg == 2) ? 0 : stg + 1;
    }
#undef STAGE

    // ---- final row-sum reduce (once per kernel) ----
    float l_run = 0.f;
#pragma unroll
    for (int e = 0; e < 16; ++e) l_run += sum16[e];
    l_run += __shfl_xor(l_run, 32);

    // ---- epilogue: out^T -> LDS (swizzled) -> coalesced global store ----
    __syncthreads();  // all waves done reading kvbuf before reuse as ob
    const float inv = 1.0f / l_run;
    unsigned short* ob = &kvbuf[0];
    const int orow = w * 32 + q31;
    const int oswz = (orow & 7) << 3;
#pragma unroll
    for (int dt = 0; dt < 2; ++dt) {
#pragma unroll
        for (int u = 0; u < 4; ++u) {
            u16x4 v4;
#pragma unroll
            for (int v = 0; v < 4; ++v)
                v4[v] = f2bf((dt ? acc1[4 * u + v] : acc0[4 * u + v]) * inv);
            const int d0 = dt * 32 + 8 * u + 4 * g;
            *(u16x4*)&ob[orow * 64 + (d0 ^ oswz)] = v4;
        }
    }
    __syncthreads();
#pragma unroll
    for (int p = 0; p < 4; ++p) {
        const int row = p * 32 + (t >> 3);
        const int c16 = t & 7;
        u16x8 v = *(const u16x8*)&ob[row * 64 + ((c16 ^ (row & 7)) * 8)];
        *(u16x8*)(att + (size_t)(b * LL + q0 + row) * DD + h * 64 + c16 * 8) = v;
    }
}

// ---------------- out GEMM: att[4096x1024] x Wo -> fp32 out ----------------
__global__ __launch_bounds__(256) void gemm_out(const unsigned short* __restrict__ Abf,
                                                const unsigned short* __restrict__ Btw,
                                                const float* __restrict__ bo,
                                                float* __restrict__ out) {
    __shared__ unsigned short Asm[128 * 32];
    __shared__ unsigned short Bsm[128 * 32];
    const int t = threadIdx.x;
    const int w = t >> 6, lane = t & 63;
    const int wm = w >> 1, wn = w & 1;
    const int lr = lane & 15, lk = (lane >> 4) * 8;
    const int row0 = blockIdx.x * 128;
    const int col0 = blockIdx.y * 128;
    const int r = t >> 2;
    const int cb8 = (t & 3) * 8;

    f32x4 acc[4][4];
#pragma unroll
    for (int mf = 0; mf < 4; ++mf)
#pragma unroll
        for (int nf = 0; nf < 4; ++nf)
#pragma unroll
            for (int e = 0; e < 4; ++e) acc[mf][nf][e] = 0.f;

    for (int kt = 0; kt < 32; ++kt) {
        __syncthreads();
        const int k0 = kt * 32;
#pragma unroll
        for (int p = 0; p < 2; ++p) {
            const unsigned short* sa = Abf + (size_t)(row0 + p * 64 + r) * 1024 + k0 + cb8;
            __builtin_amdgcn_global_load_lds(
                (const __attribute__((address_space(1))) unsigned int*)sa,
                (__attribute__((address_space(3))) unsigned int*)(Asm + p * 2048 + t * 8), 16, 0, 0);
            const unsigned short* sb = Btw + (size_t)(col0 + p * 64 + r) * 1024 + k0 + cb8;
            __builtin_amdgcn_global_load_lds(
                (const __attribute__((address_space(1))) unsigned int*)sb,
                (__attribute__((address_space(3))) unsigned int*)(Bsm + p * 2048 + t * 8), 16, 0, 0);
        }
        __syncthreads();
        bf16x8 af[4], bfr[4];
#pragma unroll
        for (int mf = 0; mf < 4; ++mf)
            af[mf] = *(const bf16x8*)&Asm[(wm * 64 + mf * 16 + lr) * 32 + lk];
#pragma unroll
        for (int nf = 0; nf < 4; ++nf)
            bfr[nf] = *(const bf16x8*)&Bsm[(wn * 64 + nf * 16 + lr) * 32 + lk];
#pragma unroll
        for (int mf = 0; mf < 4; ++mf)
#pragma unroll
            for (int nf = 0; nf < 4; ++nf)
                acc[mf][nf] = __builtin_amdgcn_mfma_f32_16x16x32_bf16(af[mf], bfr[nf], acc[mf][nf], 0, 0, 0);
    }

#pragma unroll
    for (int mf = 0; mf < 4; ++mf) {
        const int grow = row0 + wm * 64 + mf * 16 + (lane >> 4) * 4;
#pragma unroll
        for (int nf = 0; nf < 4; ++nf) {
            const int gcol = col0 + wn * 64 + nf * 16 + lr;
            const float bias = bo[gcol];
#pragma unroll
            for (int rr = 0; rr < 4; ++rr)
                out[(size_t)(grow + rr) * 1024 + gcol] = acc[mf][nf][rr] + bias;
        }
    }
}

extern "C" void kernel_launch(void* const* d_in, const int* in_sizes, int n_in,
                              void* d_out, int out_size, void* d_ws, size_t ws_size,
                              hipStream_t stream) {
    const float* x = (const float*)d_in[0];
    const int* cid = (const int*)d_in[1];
    const int* vmask = (const int*)d_in[2];
    const float* Wq = (const float*)d_in[3];
    const float* bq = (const float*)d_in[4];
    const float* Wk = (const float*)d_in[5];
    const float* bk = (const float*)d_in[6];
    const float* Wv = (const float*)d_in[7];
    const float* bv = (const float*)d_in[8];
    const float* Wo = (const float*)d_in[9];
    const float* bo = (const float*)d_in[10];
    const float* case_bias = (const float*)d_in[11];
    const float* verb_bias = (const float*)d_in[12];
    float* out = (float*)d_out;

    char* ws = (char*)d_ws;
    unsigned short* xb     = (unsigned short*)(ws);                       // 8 MB
    unsigned short* Wqkv_t = (unsigned short*)(ws + ((size_t)8 << 20));   // 6 MB
    unsigned short* Wo_t   = (unsigned short*)(ws + ((size_t)14 << 20));  // 2 MB
    unsigned short* qkv    = (unsigned short*)(ws + ((size_t)16 << 20));  // 24 MB
    unsigned short* Vt     = (unsigned short*)(ws + ((size_t)40 << 20));  // 8 MB
    unsigned short* att    = (unsigned short*)(ws + ((size_t)48 << 20));  // 8 MB
    float*          btab   = (float*)(ws + ((size_t)56 << 20));           // 2 MB

    const size_t MATSZ = (size_t)BB * HH * LL * HDD;  // 4 Mi elements

    hipLaunchKernelGGL(prep_all, dim3(16, 16, 6), dim3(256), 0, stream,
                       x, Wq, Wk, Wv, Wo, cid, vmask, case_bias, verb_bias,
                       xb, Wqkv_t, Wo_t, btab);
    hipLaunchKernelGGL(gemm_qkv, dim3(32, 24), dim3(256), 0, stream, xb, Wqkv_t, bq, bk, bv, qkv);
    hipLaunchKernelGGL(vtrans, dim3(16, 64), dim3(256), 0, stream, qkv + 2 * MATSZ, Vt);
    hipLaunchKernelGGL(attn8, dim3(512), dim3(256), 0, stream,
                       qkv, qkv + MATSZ, Vt, cid, btab, att);
    hipLaunchKernelGGL(gemm_out, dim3(32, 8), dim3(256), 0, stream, att, Wo_t, bo, out);
}